// Round 2
// baseline (289.103 us; speedup 1.0000x reference)
//
#include <hip/hip_runtime.h>
#include <hip/hip_bf16.h>

#define EMBED 128
#define TSTEPS 128
#define NBATCH 32
#define VDIM 50257
#define MROWS 4096            // NBATCH * TSTEPS
#define NCHUNKS 3142          // ceil(VDIM/16)
#define GRIDX 128
#define CHUNKS_PB 25          // ceil(NCHUNKS/GRIDX)
#define CONV_N4 ((VDIM * EMBED) / 4)          // 1608224 float4 elements
#define CONV_BLOCKS ((CONV_N4 + 255) / 256)   // 6283

static constexpr float LOG2E = 1.4426950408889634f;
static constexpr float LN2   = 0.6931471805599453f;

__device__ __forceinline__ float fast_exp2(float x) {
#if __has_builtin(__builtin_amdgcn_exp2f)
    return __builtin_amdgcn_exp2f(x);
#else
    return exp2f(x);
#endif
}
__device__ __forceinline__ float fast_log2(float x) {
#if __has_builtin(__builtin_amdgcn_logf)
    return __builtin_amdgcn_logf(x);
#else
    return log2f(x);
#endif
}
__device__ __forceinline__ unsigned short f2bf_raw(float f) {
    __hip_bfloat16 h = __float2bfloat16(f);
    union { __hip_bfloat16 b; unsigned short u; } cvt;
    cvt.b = h;
    return cvt.u;
}

// ---------------------------------------------------------------------------
// K0 (fused setup): blocks [0,32) run the sequential scan (one batch chain
// per block); blocks [32, 32+CONV_BLOCKS) convert Wv fp32->bf16; the first
// conv block also zeroes the S accumulator. The scan only occupies 32 CUs,
// so the conversion runs concurrently on the remaining 224.
// ---------------------------------------------------------------------------
__global__ __launch_bounds__(256) void setup_kernel(const int* __restrict__ zi,
                                                    const float* __restrict__ latent,
                                                    const float* __restrict__ Wt,
                                                    const float* __restrict__ bt,
                                                    const float* __restrict__ Wv,
                                                    float* __restrict__ zs_f32,
                                                    unsigned short* __restrict__ zsb,
                                                    unsigned short* __restrict__ Wvb,
                                                    float* __restrict__ S) {
    if (blockIdx.x >= NBATCH) {
        // ---- conversion / memset path ----
        const int cb = blockIdx.x - NBATCH;
        if (cb == 0) {
            // zero S: 4096 floats by 256 threads
#pragma unroll
            for (int i = 0; i < MROWS / 256; i++)
                S[i * 256 + threadIdx.x] = 0.f;
        }
        const int i = cb * 256 + threadIdx.x;
        if (i < CONV_N4) {
            float4 v = reinterpret_cast<const float4*>(Wv)[i];
            ushort4 o;
            o.x = f2bf_raw(v.x); o.y = f2bf_raw(v.y);
            o.z = f2bf_raw(v.z); o.w = f2bf_raw(v.w);
            reinterpret_cast<ushort4*>(Wvb)[i] = o;
        }
        return;
    }

    // ---- scan path: one block per batch element ----
    __shared__ float z_lds[EMBED];
    __shared__ float partial[EMBED];
    const int b = blockIdx.x;
    const int e = threadIdx.x & 127;
    const int h = threadIdx.x >> 7;

    // cache Wt[e][h*64 .. h*64+63] in registers
    float4 wrow[16];
    const float4* wt4 = reinterpret_cast<const float4*>(Wt + e * EMBED + h * 64);
#pragma unroll
    for (int i = 0; i < 16; i++) wrow[i] = wt4[i];
    const float bte = bt[e];

    if (h == 0) z_lds[e] = latent[zi[b] * EMBED + e];
    __syncthreads();

    for (int t = 0; t < TSTEPS; t++) {
        const float zc = z_lds[e];
        const long row = (long)b * TSTEPS + t;
        if (h == 0) zs_f32[row * EMBED + e] = zc;           // emit pre-update z
        else        zsb[row * EMBED + e] = f2bf_raw(zc * LOG2E);

        // half-dot: sum_k z[k] * Wt[e][k], k in [h*64, h*64+64)
        const float4* z4 = reinterpret_cast<const float4*>(z_lds + h * 64);
        float4 acc = {0.f, 0.f, 0.f, 0.f};
#pragma unroll
        for (int i = 0; i < 16; i++) {
            float4 zv = z4[i];          // LDS broadcast (wave-uniform address)
            acc.x += zv.x * wrow[i].x;
            acc.y += zv.y * wrow[i].y;
            acc.z += zv.z * wrow[i].z;
            acc.w += zv.w * wrow[i].w;
        }
        float s = acc.x + acc.y + acc.z + acc.w;
        if (h == 1) partial[e] = s;
        __syncthreads();
        if (h == 0) {
            float znew = tanhf(zc + s + partial[e] + bte);
            z_lds[e] = znew;
        }
        __syncthreads();
    }
}

// ---------------------------------------------------------------------------
// K1: fused GEMM + sum-of-exp2.  A = zsb [4096 x 128] (bf16, pre-scaled by
// log2e), B = Wvb [50257 x 128] (bf16).  Each block: 4 waves x 64 rows =
// 256 rows, a V-slice of CHUNKS_PB 16-col chunks.  A-fragments register
// resident for the whole slice; B + bias software-pipelined (prefetch next
// chunk before computing current so the vmcnt wait lands after MFMA issue).
// C init = bv*log2e.  Per-row partial sumexp -> shfl reduce -> one atomicAdd.
// mfma_f32_16x16x32_bf16 layouts (HW-verified, guide §3):
//   A: lane holds A[m=lane&15][k=(lane>>4)*8 + j], j=0..7
//   B: lane holds B[n=lane&15][k=(lane>>4)*8 + j]   (row-major [n][k] = B^T)
//   D: lane holds D[row=(lane>>4)*4 + r][col=lane&15], r=0..3
// ---------------------------------------------------------------------------
typedef __attribute__((ext_vector_type(8))) short bfrag;
typedef __attribute__((ext_vector_type(4))) float f32x4;

__global__ __launch_bounds__(256, 4) void gemm_lse_kernel(const unsigned short* __restrict__ zsb,
                                                          const unsigned short* __restrict__ Wvb,
                                                          const float* __restrict__ bv,
                                                          float* __restrict__ S) {
    const int lane  = threadIdx.x & 63;
    const int wave  = threadIdx.x >> 6;
    const int col16 = lane & 15;
    const int quad  = lane >> 4;
    const int mbase = blockIdx.y * 256 + wave * 64;

    const int chunk0 = blockIdx.x * CHUNKS_PB;
    const int chunk1 = min(chunk0 + CHUNKS_PB, NCHUNKS);
    if (chunk0 >= chunk1) return;

    // A fragments: 4 M-subtiles x 4 K-chunks, register resident (64 VGPRs)
    bfrag a[4][4];
    const short* zss = reinterpret_cast<const short*>(zsb);
#pragma unroll
    for (int s = 0; s < 4; s++)
#pragma unroll
        for (int c = 0; c < 4; c++) {
            const short* p = zss + (long)(mbase + s * 16 + col16) * EMBED + c * 32 + quad * 8;
            a[s][c] = *reinterpret_cast<const bfrag*>(p);
        }

    float sums[16];
#pragma unroll
    for (int i = 0; i < 16; i++) sums[i] = 0.f;

    const short* wvs = reinterpret_cast<const short*>(Wvb);

    // prologue: load chunk0's B fragments + bias
    int col = chunk0 * 16 + col16;
    int colc = min(col, VDIM - 1);
    float binit = (col < VDIM) ? bv[colc] * LOG2E : -1e30f;
    bfrag bf[4];
#pragma unroll
    for (int c = 0; c < 4; c++)
        bf[c] = *reinterpret_cast<const bfrag*>(wvs + (long)colc * EMBED + c * 32 + quad * 8);

    for (int nc = chunk0; nc < chunk1; nc++) {
        // prefetch next chunk (clamped on last iteration; redundant load is harmless)
        const int np    = (nc + 1 < chunk1) ? nc + 1 : nc;
        const int colp  = np * 16 + col16;
        const int colpc = min(colp, VDIM - 1);
        const float binit_n = (colp < VDIM) ? bv[colpc] * LOG2E : -1e30f;
        bfrag bfn[4];
#pragma unroll
        for (int c = 0; c < 4; c++)
            bfn[c] = *reinterpret_cast<const bfrag*>(wvs + (long)colpc * EMBED + c * 32 + quad * 8);

        // compute with current chunk (bf/binit already in registers)
#pragma unroll
        for (int s = 0; s < 4; s++) {
            f32x4 d = {binit, binit, binit, binit};
#pragma unroll
            for (int c = 0; c < 4; c++)
                d = __builtin_amdgcn_mfma_f32_16x16x32_bf16(a[s][c], bf[c], d, 0, 0, 0);
#pragma unroll
            for (int r = 0; r < 4; r++)
                sums[s * 4 + r] += fast_exp2(d[r]);
        }

        // rotate pipeline registers (vmcnt wait lands here, after compute issue)
#pragma unroll
        for (int c = 0; c < 4; c++) bf[c] = bfn[c];
        binit = binit_n;
    }

    // reduce partial sums over the 16 columns (lanes within each quad group)
#pragma unroll
    for (int s = 0; s < 4; s++) {
#pragma unroll
        for (int r = 0; r < 4; r++) {
            float v = sums[s * 4 + r];
            v += __shfl_xor(v, 1);
            v += __shfl_xor(v, 2);
            v += __shfl_xor(v, 4);
            v += __shfl_xor(v, 8);
            if (col16 == 0)
                atomicAdd(&S[mbase + s * 16 + quad * 4 + r], v);
        }
    }
}

// ---------------------------------------------------------------------------
// K2: yp[row] = (zs[row] . Wv[y[row]] + bv[y[row]]) - ln2 * log2(S[row])
// Target dot in full fp32 (the error-dominant term).  One wave per row.
// ---------------------------------------------------------------------------
__global__ __launch_bounds__(256) void tail_kernel(const float* __restrict__ zs,
                                                   const float* __restrict__ Wv,
                                                   const float* __restrict__ bv,
                                                   const int* __restrict__ y,
                                                   const float* __restrict__ S,
                                                   float* __restrict__ out) {
    const int row  = blockIdx.x * 4 + (threadIdx.x >> 6);
    const int lane = threadIdx.x & 63;
    const int yv = y[row];
    const float* zr = zs + (long)row * EMBED;
    const float* wr = Wv + (long)yv * EMBED;
    float v = zr[lane] * wr[lane] + zr[lane + 64] * wr[lane + 64];
    v += __shfl_xor(v, 32);
    v += __shfl_xor(v, 16);
    v += __shfl_xor(v, 8);
    v += __shfl_xor(v, 4);
    v += __shfl_xor(v, 2);
    v += __shfl_xor(v, 1);
    if (lane == 0)
        out[row] = v + bv[yv] - LN2 * fast_log2(S[row]);
}

// ---------------------------------------------------------------------------
extern "C" void kernel_launch(void* const* d_in, const int* in_sizes, int n_in,
                              void* d_out, int out_size, void* d_ws, size_t ws_size,
                              hipStream_t stream) {
    const int*   zi     = (const int*)d_in[0];
    const int*   y      = (const int*)d_in[1];
    const float* latent = (const float*)d_in[2];
    const float* Wt     = (const float*)d_in[3];
    const float* bt     = (const float*)d_in[4];
    const float* Wv     = (const float*)d_in[5];
    const float* bv     = (const float*)d_in[6];
    float* out = (float*)d_out;

    char* ws = (char*)d_ws;
    // workspace layout (~16.05 MB total):
    float*          zs_f32 = (float*)ws;                              // 2 MB
    unsigned short* zsb    = (unsigned short*)(ws + (2u << 20));      // 1 MB
    unsigned short* wvb    = (unsigned short*)(ws + (3u << 20));      // 12.27 MB
    float*          S      = (float*)(ws + (16u << 20));              // 16 KB

    setup_kernel<<<NBATCH + CONV_BLOCKS, 256, 0, stream>>>(zi, latent, Wt, bt, Wv,
                                                           zs_f32, zsb, wvb, S);

    gemm_lse_kernel<<<dim3(GRIDX, MROWS / 256), 256, 0, stream>>>(zsb, wvb, bv, S);

    tail_kernel<<<MROWS / 4, 256, 0, stream>>>(zs_f32, Wv, bv, y, S, out);
}

// Round 3
// 267.869 us; speedup vs baseline: 1.0793x; 1.0793x over previous
//
#include <hip/hip_runtime.h>
#include <hip/hip_bf16.h>
#include <hip/hip_fp16.h>

#define EMBED 128
#define TSTEPS 128
#define NBATCH 32
#define VDIM 50257
#define VPAD 50304            // 786 groups * 64 cols
#define MROWS 4096            // NBATCH * TSTEPS
#define NGROUPS 786           // VPAD / 64
#define GRIDX 64
#define GRIDY 16
#define CONV_N4 ((VDIM * EMBED) / 4)          // 1608224 float4 elements
#define CONV_BLOCKS ((CONV_N4 + 255) / 256)   // 6283

static constexpr float LOG2E = 1.4426950408889634f;
static constexpr float LN2   = 0.6931471805599453f;

__device__ __forceinline__ float fast_exp2(float x) {
#if __has_builtin(__builtin_amdgcn_exp2f)
    return __builtin_amdgcn_exp2f(x);
#else
    return exp2f(x);
#endif
}
__device__ __forceinline__ float fast_log2(float x) {
#if __has_builtin(__builtin_amdgcn_logf)
    return __builtin_amdgcn_logf(x);
#else
    return log2f(x);
#endif
}
__device__ __forceinline__ unsigned short f2bf_raw(float f) {
    __hip_bfloat16 h = __float2bfloat16(f);
    union { __hip_bfloat16 b; unsigned short u; } cvt;
    cvt.b = h;
    return cvt.u;
}

// ---------------------------------------------------------------------------
// K0 (fused setup): blocks [0,32) = sequential scan (one batch chain each);
// blocks [32, 32+CONV_BLOCKS) convert Wv fp32->bf16, write the bf16 zero pad
// rows [VDIM,VPAD), build the prescaled/padded bias array, and zero S.
// ---------------------------------------------------------------------------
__global__ __launch_bounds__(256) void setup_kernel(const int* __restrict__ zi,
                                                    const float* __restrict__ latent,
                                                    const float* __restrict__ Wt,
                                                    const float* __restrict__ bt,
                                                    const float* __restrict__ Wv,
                                                    const float* __restrict__ bv,
                                                    unsigned short* __restrict__ zsh,
                                                    unsigned short* __restrict__ zsb,
                                                    unsigned short* __restrict__ Wvb,
                                                    float* __restrict__ bvs,
                                                    float* __restrict__ S) {
    if (blockIdx.x >= NBATCH) {
        const int cb = blockIdx.x - NBATCH;
        if (cb == 0) {                      // zero the S accumulator
#pragma unroll
            for (int i = 0; i < MROWS / 256; i++)
                S[i * 256 + threadIdx.x] = 0.f;
        }
        if (cb == 1) {                      // zero pad rows of Wvb
            const int base4 = (VDIM * EMBED) / 4;     // first pad ushort4
            const int npad4 = ((VPAD - VDIM) * EMBED) / 4;
            for (int i = threadIdx.x; i < npad4; i += 256)
                reinterpret_cast<ushort4*>(Wvb)[base4 + i] = make_ushort4(0, 0, 0, 0);
        }
        const int idx = cb * 256 + threadIdx.x;
        if (idx < VPAD)                     // prescaled, padded bias
            bvs[idx] = (idx < VDIM) ? bv[idx] * LOG2E : -1e30f;
        if (idx < CONV_N4) {
            float4 v = reinterpret_cast<const float4*>(Wv)[idx];
            ushort4 o;
            o.x = f2bf_raw(v.x); o.y = f2bf_raw(v.y);
            o.z = f2bf_raw(v.z); o.w = f2bf_raw(v.w);
            reinterpret_cast<ushort4*>(Wvb)[idx] = o;
        }
        return;
    }

    // ---- scan path: one block per batch element ----
    __shared__ float z_lds[EMBED];
    __shared__ float partial[EMBED];
    const int b = blockIdx.x;
    const int e = threadIdx.x & 127;
    const int h = threadIdx.x >> 7;

    float4 wrow[16];
    const float4* wt4 = reinterpret_cast<const float4*>(Wt + e * EMBED + h * 64);
#pragma unroll
    for (int i = 0; i < 16; i++) wrow[i] = wt4[i];
    const float bte = bt[e];

    if (h == 0) z_lds[e] = latent[zi[b] * EMBED + e];
    __syncthreads();

    for (int t = 0; t < TSTEPS; t++) {
        const float zc = z_lds[e];
        const long row = (long)b * TSTEPS + t;
        if (h == 0) {
            __half zh = __float2half(zc);
            zsh[row * EMBED + e] = *reinterpret_cast<unsigned short*>(&zh);
        } else {
            zsb[row * EMBED + e] = f2bf_raw(zc * LOG2E);
        }

        const float4* z4 = reinterpret_cast<const float4*>(z_lds + h * 64);
        float4 acc = {0.f, 0.f, 0.f, 0.f};
#pragma unroll
        for (int i = 0; i < 16; i++) {
            float4 zv = z4[i];
            acc.x += zv.x * wrow[i].x;
            acc.y += zv.y * wrow[i].y;
            acc.z += zv.z * wrow[i].z;
            acc.w += zv.w * wrow[i].w;
        }
        float s = acc.x + acc.y + acc.z + acc.w;
        if (h == 1) partial[e] = s;
        __syncthreads();
        if (h == 0) {
            float znew = tanhf(zc + s + partial[e] + bte);
            z_lds[e] = znew;
        }
        __syncthreads();
    }
}

// ---------------------------------------------------------------------------
// K1: fused GEMM + sum-of-exp2.  A = zsb [4096 x 128] bf16 (prescaled by
// log2e), B = Wvb [VPAD x 128] bf16 (zero-padded).  Block: 4 waves x 64 rows
// = 256 rows, 12-13 groups of 4 N-chunks (64 cols).  Per group: ALL 16
// B-frag loads + 4 bias loads issued together (4x MLP vs per-chunk), then 64
// MFMAs + 64 exp2.  Bias folded into accumulator init (pad bias = -1e30 ->
// exp2 -> 0, so pad columns contribute nothing).  No clamps in the hot loop.
// No launch_bounds reg cap: ~170 VGPRs must NOT spill (round-2 regression
// was the (256,4) cap forcing spills).
// mfma_f32_16x16x32_bf16 layouts (HW-verified, guide §3):
//   A: lane holds A[m=lane&15][k=(lane>>4)*8 + j], j=0..7
//   B: lane holds B[n=lane&15][k=(lane>>4)*8 + j]
//   D: lane holds D[row=(lane>>4)*4 + r][col=lane&15], r=0..3
// ---------------------------------------------------------------------------
typedef __attribute__((ext_vector_type(8))) short bfrag;
typedef __attribute__((ext_vector_type(4))) float f32x4;

__global__ __launch_bounds__(256) void gemm_lse_kernel(const unsigned short* __restrict__ zsb,
                                                       const unsigned short* __restrict__ Wvb,
                                                       const float* __restrict__ bvs,
                                                       float* __restrict__ S) {
    const int lane  = threadIdx.x & 63;
    const int wave  = threadIdx.x >> 6;
    const int col16 = lane & 15;
    const int quad  = lane >> 4;
    const int mbase = blockIdx.y * 256 + wave * 64;

    // A fragments: 4 M-subtiles x 4 K-chunks, register resident (64 VGPRs)
    bfrag a[4][4];
    const short* zss = reinterpret_cast<const short*>(zsb);
#pragma unroll
    for (int s = 0; s < 4; s++)
#pragma unroll
        for (int c = 0; c < 4; c++) {
            const short* p = zss + (long)(mbase + s * 16 + col16) * EMBED + c * 32 + quad * 8;
            a[s][c] = *reinterpret_cast<const bfrag*>(p);
        }

    float sums[16];
#pragma unroll
    for (int i = 0; i < 16; i++) sums[i] = 0.f;

    // group range for this x-block: 786 = 64*12 + 18
    const int x  = blockIdx.x;
    const int g0 = x * 12 + min(x, 18);
    const int g1 = g0 + 12 + (x < 18 ? 1 : 0);

    const short* wvs = reinterpret_cast<const short*>(Wvb);

    for (int g = g0; g < g1; g++) {
        const int colbase = g * 64;

        // ---- load phase: 16 B-frag loads + 4 bias loads, all independent ----
        bfrag bf[4][4];
        float bvl[4];
#pragma unroll
        for (int c = 0; c < 4; c++) {
            const short* bp = wvs + (long)(colbase + c * 16 + col16) * EMBED + quad * 8;
#pragma unroll
            for (int kc = 0; kc < 4; kc++)
                bf[c][kc] = *reinterpret_cast<const bfrag*>(bp + kc * 32);
            bvl[c] = bvs[colbase + c * 16 + col16];
        }

        // ---- compute phase: 64 MFMA + 64 exp2 ----
#pragma unroll
        for (int c = 0; c < 4; c++) {
#pragma unroll
            for (int s = 0; s < 4; s++) {
                f32x4 d = {bvl[c], bvl[c], bvl[c], bvl[c]};
#pragma unroll
                for (int kc = 0; kc < 4; kc++)
                    d = __builtin_amdgcn_mfma_f32_16x16x32_bf16(a[s][kc], bf[c][kc], d, 0, 0, 0);
#pragma unroll
                for (int r = 0; r < 4; r++)
                    sums[s * 4 + r] += fast_exp2(d[r]);
            }
        }
    }

    // reduce partial sums over the 16 columns, one atomic per row per block
#pragma unroll
    for (int s = 0; s < 4; s++) {
#pragma unroll
        for (int r = 0; r < 4; r++) {
            float v = sums[s * 4 + r];
            v += __shfl_xor(v, 1);
            v += __shfl_xor(v, 2);
            v += __shfl_xor(v, 4);
            v += __shfl_xor(v, 8);
            if (col16 == 0)
                atomicAdd(&S[mbase + s * 16 + quad * 4 + r], v);
        }
    }
}

// ---------------------------------------------------------------------------
// K2: yp[row] = (zs[row] . Wv[y[row]] + bv[y[row]]) - ln2 * log2(S[row])
// Target dot from fp16 zs x fp32 Wv in fp32 (err ~0.015 << 0.28 budget).
// One wave per row; lane l handles elements {2l, 2l+1}.
// ---------------------------------------------------------------------------
__global__ __launch_bounds__(256) void tail_kernel(const unsigned short* __restrict__ zsh,
                                                   const float* __restrict__ Wv,
                                                   const float* __restrict__ bv,
                                                   const int* __restrict__ y,
                                                   const float* __restrict__ S,
                                                   float* __restrict__ out) {
    const int row  = blockIdx.x * 4 + (threadIdx.x >> 6);
    const int lane = threadIdx.x & 63;
    const int yv = y[row];
    const __half2* zr = reinterpret_cast<const __half2*>(zsh + (long)row * EMBED);
    const float2*  wr = reinterpret_cast<const float2*>(Wv + (long)yv * EMBED);
    __half2 z2 = zr[lane];
    float2  w2 = wr[lane];
    float v = __half2float(z2.x) * w2.x + __half2float(z2.y) * w2.y;
    v += __shfl_xor(v, 32);
    v += __shfl_xor(v, 16);
    v += __shfl_xor(v, 8);
    v += __shfl_xor(v, 4);
    v += __shfl_xor(v, 2);
    v += __shfl_xor(v, 1);
    if (lane == 0)
        out[row] = v + bv[yv] - LN2 * fast_log2(S[row]);
}

// ---------------------------------------------------------------------------
extern "C" void kernel_launch(void* const* d_in, const int* in_sizes, int n_in,
                              void* d_out, int out_size, void* d_ws, size_t ws_size,
                              hipStream_t stream) {
    const int*   zi     = (const int*)d_in[0];
    const int*   y      = (const int*)d_in[1];
    const float* latent = (const float*)d_in[2];
    const float* Wt     = (const float*)d_in[3];
    const float* bt     = (const float*)d_in[4];
    const float* Wv     = (const float*)d_in[5];
    const float* bv     = (const float*)d_in[6];
    float* out = (float*)d_out;

    char* ws = (char*)d_ws;
    // workspace layout (~15.3 MB total):
    unsigned short* zsb = (unsigned short*)ws;                         // 1 MB   @ 0
    unsigned short* zsh = (unsigned short*)(ws + (1u << 20));          // 1 MB   @ 1M
    float*          S   = (float*)(ws + (2u << 20));                   // 16 KB  @ 2M
    float*          bvs = (float*)(ws + (2u << 20) + (64u << 10));     // 197 KB @ 2M+64K
    unsigned short* wvb = (unsigned short*)(ws + (3u << 20));          // 12.28MB@ 3M

    setup_kernel<<<NBATCH + CONV_BLOCKS, 256, 0, stream>>>(zi, latent, Wt, bt, Wv, bv,
                                                           zsh, zsb, wvb, bvs, S);

    gemm_lse_kernel<<<dim3(GRIDX, GRIDY), 256, 0, stream>>>(zsb, wvb, bvs, S);

    tail_kernel<<<MROWS / 4, 256, 0, stream>>>(zsh, Wv, bv, y, S, out);
}

// Round 5
// 225.100 us; speedup vs baseline: 1.2843x; 1.1900x over previous
//
#include <hip/hip_runtime.h>
#include <hip/hip_bf16.h>
#include <hip/hip_fp16.h>

#define EMBED 128
#define TSTEPS 128
#define NBATCH 32
#define VDIM 50257
#define VPAD 50304            // 786 groups * 64 cols
#define MROWS 4096            // NBATCH * TSTEPS
#define NGROUPS 786           // VPAD / 64
#define GRIDX 64
#define GRIDY 16
#define CONV_N4 ((VDIM * EMBED) / 4)          // 1608224 float4 elements
#define CONV_BLOCKS ((CONV_N4 + 255) / 256)   // 6283

static constexpr float LOG2E = 1.4426950408889634f;
static constexpr float LN2   = 0.6931471805599453f;

__device__ __forceinline__ float fast_exp2(float x) {
#if __has_builtin(__builtin_amdgcn_exp2f)
    return __builtin_amdgcn_exp2f(x);
#else
    return exp2f(x);
#endif
}
__device__ __forceinline__ float fast_log2(float x) {
#if __has_builtin(__builtin_amdgcn_logf)
    return __builtin_amdgcn_logf(x);
#else
    return log2f(x);
#endif
}
__device__ __forceinline__ unsigned short f2bf_raw(float f) {
    __hip_bfloat16 h = __float2bfloat16(f);
    union { __hip_bfloat16 b; unsigned short u; } cvt;
    cvt.b = h;
    return cvt.u;
}

// ---------------------------------------------------------------------------
// K0 (fused setup): blocks [0,32) = sequential scan (one batch chain each);
// blocks [32, 32+CONV_BLOCKS) convert Wv fp32->bf16, write the bf16 zero pad
// rows [VDIM,VPAD), build the prescaled/padded bias array, and zero S.
// NOTE: the scan MUST use exact libm tanhf. Round-4's fast_tanh (exp2+rcp,
// ~1e-6/step) amplified through 128 recurrence steps to ~0.2 absmax drift
// and failed the 0.28 threshold. Do not approximate inside the recurrence.
// ---------------------------------------------------------------------------
__global__ __launch_bounds__(256) void setup_kernel(const int* __restrict__ zi,
                                                    const float* __restrict__ latent,
                                                    const float* __restrict__ Wt,
                                                    const float* __restrict__ bt,
                                                    const float* __restrict__ Wv,
                                                    const float* __restrict__ bv,
                                                    unsigned short* __restrict__ zsh,
                                                    unsigned short* __restrict__ zsb,
                                                    unsigned short* __restrict__ Wvb,
                                                    float* __restrict__ bvs,
                                                    float* __restrict__ S) {
    if (blockIdx.x >= NBATCH) {
        const int cb = blockIdx.x - NBATCH;
        if (cb == 0) {                      // zero the S accumulator
#pragma unroll
            for (int i = 0; i < MROWS / 256; i++)
                S[i * 256 + threadIdx.x] = 0.f;
        }
        if (cb == 1) {                      // zero pad rows of Wvb
            const int base4 = (VDIM * EMBED) / 4;     // first pad ushort4
            const int npad4 = ((VPAD - VDIM) * EMBED) / 4;
            for (int i = threadIdx.x; i < npad4; i += 256)
                reinterpret_cast<ushort4*>(Wvb)[base4 + i] = make_ushort4(0, 0, 0, 0);
        }
        const int idx = cb * 256 + threadIdx.x;
        if (idx < VPAD)                     // prescaled, padded bias
            bvs[idx] = (idx < VDIM) ? bv[idx] * LOG2E : -1e30f;
        if (idx < CONV_N4) {
            float4 v = reinterpret_cast<const float4*>(Wv)[idx];
            ushort4 o;
            o.x = f2bf_raw(v.x); o.y = f2bf_raw(v.y);
            o.z = f2bf_raw(v.z); o.w = f2bf_raw(v.w);
            reinterpret_cast<ushort4*>(Wvb)[idx] = o;
        }
        return;
    }

    // ---- scan path: one block per batch element ----
    __shared__ float z_lds[EMBED];
    __shared__ float partial[EMBED];
    const int b = blockIdx.x;
    const int e = threadIdx.x & 127;
    const int h = threadIdx.x >> 7;

    float4 wrow[16];
    const float4* wt4 = reinterpret_cast<const float4*>(Wt + e * EMBED + h * 64);
#pragma unroll
    for (int i = 0; i < 16; i++) wrow[i] = wt4[i];
    const float bte = bt[e];

    if (h == 0) z_lds[e] = latent[zi[b] * EMBED + e];
    __syncthreads();

    for (int t = 0; t < TSTEPS; t++) {
        const float zc = z_lds[e];
        const long row = (long)b * TSTEPS + t;
        if (h == 0) {
            __half zh = __float2half(zc);
            zsh[row * EMBED + e] = *reinterpret_cast<unsigned short*>(&zh);
        } else {
            zsb[row * EMBED + e] = f2bf_raw(zc * LOG2E);
        }

        const float4* z4 = reinterpret_cast<const float4*>(z_lds + h * 64);
        float4 acc = {0.f, 0.f, 0.f, 0.f};
#pragma unroll
        for (int i = 0; i < 16; i++) {
            float4 zv = z4[i];
            acc.x += zv.x * wrow[i].x;
            acc.y += zv.y * wrow[i].y;
            acc.z += zv.z * wrow[i].z;
            acc.w += zv.w * wrow[i].w;
        }
        float s = acc.x + acc.y + acc.z + acc.w;
        if (h == 1) partial[e] = s;
        __syncthreads();
        if (h == 0) {
            float znew = tanhf(zc + s + partial[e] + bte);   // exact libm tanh
            z_lds[e] = znew;
        }
        __syncthreads();
    }
}

// ---------------------------------------------------------------------------
// K1: fused GEMM + sum-of-exp2, LDS-staged B (double-buffered).
// A = zsb [4096 x 128] bf16 (prescaled by log2e), register-resident per wave.
// B = Wvb [VPAD x 128] bf16 (zero-padded).  Block: 4 waves x 64 rows = 256
// rows x 12-13 groups of 64 N-cols.  Per group the block cooperatively DMAs
// the 16 KB B-tile into LDS via global_load_lds width=16 (contiguous 1 KB
// per wave-instr => coalesced), with an XOR-16 granule swizzle so the
// strided ds_read_b128 fragment reads are bank-conflict-free:
//   physical granule (r, q) holds logical granule (r, q ^ (r & 15)).
// Double-buffer: stage group g+1 while computing group g (one barrier/iter).
// Removes the round-1..3 bottleneck: 4x redundant per-wave B loads
// (787 MB of scattered L2 reads -> 197 MB coalesced + LDS broadcast).
// mfma_f32_16x16x32_bf16 layouts (HW-verified, guide §3):
//   A: lane holds A[m=lane&15][k=(lane>>4)*8 + j], j=0..7
//   B: lane holds B[n=lane&15][k=(lane>>4)*8 + j]
//   D: lane holds D[row=(lane>>4)*4 + r][col=lane&15], r=0..3
// ---------------------------------------------------------------------------
typedef __attribute__((ext_vector_type(8))) short bfrag;
typedef __attribute__((ext_vector_type(4))) float f32x4;

__global__ __launch_bounds__(256) void gemm_lse_kernel(const unsigned short* __restrict__ zsb,
                                                       const unsigned short* __restrict__ Wvb,
                                                       const float* __restrict__ bvs,
                                                       float* __restrict__ S) {
    __shared__ short ldsb[2][8192];          // 2 x 16 KB B tiles

    const int lane  = threadIdx.x & 63;
    const int wave  = threadIdx.x >> 6;
    const int col16 = lane & 15;
    const int quad  = lane >> 4;
    const int mbase = blockIdx.y * 256 + wave * 64;

    // A fragments: 4 M-subtiles x 4 K-chunks, register resident (64 VGPRs)
    bfrag a[4][4];
    const short* zss = reinterpret_cast<const short*>(zsb);
#pragma unroll
    for (int s = 0; s < 4; s++)
#pragma unroll
        for (int c = 0; c < 4; c++) {
            const short* p = zss + (long)(mbase + s * 16 + col16) * EMBED + c * 32 + quad * 8;
            a[s][c] = *reinterpret_cast<const bfrag*>(p);
        }

    float sums[16];
#pragma unroll
    for (int i = 0; i < 16; i++) sums[i] = 0.f;

    // group range for this x-block: 786 = 64*12 + 18
    const int x  = blockIdx.x;
    const int g0 = x * 12 + min(x, 18);
    const int g1 = g0 + 12 + (x < 18 ? 1 : 0);

    const short* wvs = reinterpret_cast<const short*>(Wvb);

    // stage group g's 16 KB B-tile into ldsb[buf] (swizzled, coalesced)
    auto stage = [&](int buf, int g) {
#pragma unroll
        for (int j = 0; j < 4; j++) {
            // this wave-instr covers physical granules s = (wave*4+j)*64 + lane
            // -> rows r = (wave*4+j)*4 + quad, phys col q = col16
            const int r   = (wave * 4 + j) * 4 + quad;
            const int swz = col16 ^ (r & 15);          // logical granule col
            const short* gp = wvs + (long)(g * 64 + r) * EMBED + swz * 8;
            __builtin_amdgcn_global_load_lds(
                (const __attribute__((address_space(1))) void*)gp,
                (__attribute__((address_space(3))) void*)&ldsb[buf][(wave * 4 + j) * 512],
                16, 0, 0);
        }
    };

    int cur = 0;
    stage(0, g0);

    for (int g = g0; g < g1; g++) {
        __syncthreads();                     // buf[cur] staged; prev reads done
        if (g + 1 < g1) stage(cur ^ 1, g + 1);

        const int colbase = g * 64;
        float bvl[4];
#pragma unroll
        for (int c = 0; c < 4; c++) bvl[c] = bvs[colbase + c * 16 + col16];

#pragma unroll
        for (int c = 0; c < 4; c++) {
            // fragment reads: logical (r = c*16+col16, kpart = kc*4+quad),
            // physical col = kpart ^ (r&15) = kpart ^ col16
            bfrag bf[4];
#pragma unroll
            for (int kc = 0; kc < 4; kc++)
                bf[kc] = *reinterpret_cast<const bfrag*>(
                    &ldsb[cur][(c * 16 + col16) * 128 + (((kc * 4 + quad) ^ col16) * 8)]);
#pragma unroll
            for (int s = 0; s < 4; s++) {
                f32x4 d = {bvl[c], bvl[c], bvl[c], bvl[c]};
#pragma unroll
                for (int kc = 0; kc < 4; kc++)
                    d = __builtin_amdgcn_mfma_f32_16x16x32_bf16(a[s][kc], bf[kc], d, 0, 0, 0);
#pragma unroll
                for (int r = 0; r < 4; r++)
                    sums[s * 4 + r] += fast_exp2(d[r]);
            }
        }
        cur ^= 1;
    }

    // reduce partial sums over the 16 columns, one atomic per row per block
#pragma unroll
    for (int s = 0; s < 4; s++) {
#pragma unroll
        for (int r = 0; r < 4; r++) {
            float v = sums[s * 4 + r];
            v += __shfl_xor(v, 1);
            v += __shfl_xor(v, 2);
            v += __shfl_xor(v, 4);
            v += __shfl_xor(v, 8);
            if (col16 == 0)
                atomicAdd(&S[mbase + s * 16 + quad * 4 + r], v);
        }
    }
}

// ---------------------------------------------------------------------------
// K2: yp[row] = (zs[row] . Wv[y[row]] + bv[y[row]]) - ln2 * log2(S[row])
// Target dot from fp16 zs x fp32 Wv in fp32 (err ~0.015 << 0.28 budget).
// One wave per row; lane l handles elements {2l, 2l+1}.
// ---------------------------------------------------------------------------
__global__ __launch_bounds__(256) void tail_kernel(const unsigned short* __restrict__ zsh,
                                                   const float* __restrict__ Wv,
                                                   const float* __restrict__ bv,
                                                   const int* __restrict__ y,
                                                   const float* __restrict__ S,
                                                   float* __restrict__ out) {
    const int row  = blockIdx.x * 4 + (threadIdx.x >> 6);
    const int lane = threadIdx.x & 63;
    const int yv = y[row];
    const __half2* zr = reinterpret_cast<const __half2*>(zsh + (long)row * EMBED);
    const float2*  wr = reinterpret_cast<const float2*>(Wv + (long)yv * EMBED);
    __half2 z2 = zr[lane];
    float2  w2 = wr[lane];
    float v = __half2float(z2.x) * w2.x + __half2float(z2.y) * w2.y;
    v += __shfl_xor(v, 32);
    v += __shfl_xor(v, 16);
    v += __shfl_xor(v, 8);
    v += __shfl_xor(v, 4);
    v += __shfl_xor(v, 2);
    v += __shfl_xor(v, 1);
    if (lane == 0)
        out[row] = v + bv[yv] - LN2 * fast_log2(S[row]);
}

// ---------------------------------------------------------------------------
extern "C" void kernel_launch(void* const* d_in, const int* in_sizes, int n_in,
                              void* d_out, int out_size, void* d_ws, size_t ws_size,
                              hipStream_t stream) {
    const int*   zi     = (const int*)d_in[0];
    const int*   y      = (const int*)d_in[1];
    const float* latent = (const float*)d_in[2];
    const float* Wt     = (const float*)d_in[3];
    const float* bt     = (const float*)d_in[4];
    const float* Wv     = (const float*)d_in[5];
    const float* bv     = (const float*)d_in[6];
    float* out = (float*)d_out;

    char* ws = (char*)d_ws;
    // workspace layout (~15.3 MB total):
    unsigned short* zsb = (unsigned short*)ws;                         // 1 MB   @ 0
    unsigned short* zsh = (unsigned short*)(ws + (1u << 20));          // 1 MB   @ 1M
    float*          S   = (float*)(ws + (2u << 20));                   // 16 KB  @ 2M
    float*          bvs = (float*)(ws + (2u << 20) + (64u << 10));     // 197 KB @ 2M+64K
    unsigned short* wvb = (unsigned short*)(ws + (3u << 20));          // 12.28MB@ 3M

    setup_kernel<<<NBATCH + CONV_BLOCKS, 256, 0, stream>>>(zi, latent, Wt, bt, Wv, bv,
                                                           zsh, zsb, wvb, bvs, S);

    gemm_lse_kernel<<<dim3(GRIDX, GRIDY), 256, 0, stream>>>(zsb, wvb, bvs, S);

    tail_kernel<<<MROWS / 4, 256, 0, stream>>>(zsh, Wv, bv, y, S, out);
}

// Round 6
// 216.064 us; speedup vs baseline: 1.3380x; 1.0418x over previous
//
#include <hip/hip_runtime.h>
#include <hip/hip_bf16.h>
#include <hip/hip_fp16.h>

#define EMBED 128
#define TSTEPS 128
#define NBATCH 32
#define VDIM 50257
#define VPAD 50304            // 786 groups * 64 cols
#define MROWS 4096            // NBATCH * TSTEPS
#define NGROUPS 786           // VPAD / 64
#define GRIDX 64
#define GRIDY 16
#define CONV_N4 ((VDIM * EMBED) / 4)          // 1608224 float4 elements
#define CONV_BLOCKS ((CONV_N4 + 255) / 256)   // 6283

static constexpr float LOG2E = 1.4426950408889634f;
static constexpr float LN2   = 0.6931471805599453f;

__device__ __forceinline__ float fast_exp2(float x) {
#if __has_builtin(__builtin_amdgcn_exp2f)
    return __builtin_amdgcn_exp2f(x);
#else
    return exp2f(x);
#endif
}
__device__ __forceinline__ float fast_log2(float x) {
#if __has_builtin(__builtin_amdgcn_logf)
    return __builtin_amdgcn_logf(x);
#else
    return log2f(x);
#endif
}
__device__ __forceinline__ unsigned short f2bf_raw(float f) {
    __hip_bfloat16 h = __float2bfloat16(f);
    union { __hip_bfloat16 b; unsigned short u; } cvt;
    cvt.b = h;
    return cvt.u;
}
__device__ __forceinline__ float bf_raw2f(unsigned short u) {
    union { unsigned int u; float f; } cvt;
    cvt.u = ((unsigned int)u) << 16;
    return cvt.f;
}

// ---------------------------------------------------------------------------
// K0 (fused setup): blocks [0,32) = sequential scan (one batch chain each);
// blocks [32, 32+CONV_BLOCKS) convert Wv fp32->bf16, write the bf16 zero pad
// rows [VDIM,VPAD), build the prescaled/padded bias array, and zero S.
//
// Scan structure (round 6): e = tid>>1, h = tid&1 -> the two k-halves of an
// output element sit in ADJACENT lanes, so the half-dots combine with one
// shfl_xor instead of an LDS round trip; z is ping-pong buffered so each
// step needs exactly ONE __syncthreads.  The fp32 summation order
// ((zc + s_h0) + s_h1) + bt matches rounds 1/3/5 bit-exactly: the recurrence
// is a ~1e6x error amplifier (round-4 fast_tanh failure), so the trajectory
// must not be perturbed.  tanhf stays libm for the same reason.
// ---------------------------------------------------------------------------
__global__ __launch_bounds__(256) void setup_kernel(const int* __restrict__ zi,
                                                    const float* __restrict__ latent,
                                                    const float* __restrict__ Wt,
                                                    const float* __restrict__ bt,
                                                    const float* __restrict__ Wv,
                                                    const float* __restrict__ bv,
                                                    unsigned short* __restrict__ zsb,
                                                    unsigned short* __restrict__ Wvb,
                                                    float* __restrict__ bvs,
                                                    float* __restrict__ S) {
    if (blockIdx.x >= NBATCH) {
        const int cb = blockIdx.x - NBATCH;
        if (cb == 0) {                      // zero the S accumulator
#pragma unroll
            for (int i = 0; i < MROWS / 256; i++)
                S[i * 256 + threadIdx.x] = 0.f;
        }
        if (cb == 1) {                      // zero pad rows of Wvb
            const int base4 = (VDIM * EMBED) / 4;     // first pad ushort4
            const int npad4 = ((VPAD - VDIM) * EMBED) / 4;
            for (int i = threadIdx.x; i < npad4; i += 256)
                reinterpret_cast<ushort4*>(Wvb)[base4 + i] = make_ushort4(0, 0, 0, 0);
        }
        const int idx = cb * 256 + threadIdx.x;
        if (idx < VPAD)                     // prescaled, padded bias
            bvs[idx] = (idx < VDIM) ? bv[idx] * LOG2E : -1e30f;
        if (idx < CONV_N4) {
            float4 v = reinterpret_cast<const float4*>(Wv)[idx];
            ushort4 o;
            o.x = f2bf_raw(v.x); o.y = f2bf_raw(v.y);
            o.z = f2bf_raw(v.z); o.w = f2bf_raw(v.w);
            reinterpret_cast<ushort4*>(Wvb)[idx] = o;
        }
        return;
    }

    // ---- scan path: one block per batch element ----
    __shared__ float zbuf[2][EMBED];
    const int b = blockIdx.x;
    const int e = threadIdx.x >> 1;     // output element 0..127
    const int h = threadIdx.x & 1;      // k-half

    // cache Wt[e][h*64 .. h*64+63] in registers (64 VGPRs)
    float4 wrow[16];
    const float4* wt4 = reinterpret_cast<const float4*>(Wt + e * EMBED + h * 64);
#pragma unroll
    for (int i = 0; i < 16; i++) wrow[i] = wt4[i];
    const float bte = bt[e];

    if (h == 0) zbuf[0][e] = latent[zi[b] * EMBED + e];
    __syncthreads();

    int cur = 0;
    for (int t = 0; t < TSTEPS; t++) {
        const float zc = zbuf[cur][e];      // lane pairs broadcast
        const long row = (long)b * TSTEPS + t;
        if (h == 0)                         // emit pre-update z (bf16 * log2e)
            zsb[row * EMBED + e] = f2bf_raw(zc * LOG2E);

        // half-dot over k in [h*64, h*64+64)
        const float4* z4 = reinterpret_cast<const float4*>(&zbuf[cur][h * 64]);
        float4 acc = {0.f, 0.f, 0.f, 0.f};
#pragma unroll
        for (int i = 0; i < 16; i++) {
            float4 zv = z4[i];
            acc.x += zv.x * wrow[i].x;
            acc.y += zv.y * wrow[i].y;
            acc.z += zv.z * wrow[i].z;
            acc.w += zv.w * wrow[i].w;
        }
        float v = acc.x + acc.y + acc.z + acc.w;
        float p = __shfl_xor(v, 1);         // partner half (same e, other h)
        float sA = h ? p : v;               // first-half dot
        float sB = h ? v : p;               // second-half dot
        // summation order identical to rounds 1/3/5 (bit-exact trajectory)
        float znew = tanhf(((zc + sA) + sB) + bte);   // exact libm tanh
        if (h == 0) zbuf[cur ^ 1][e] = znew;
        __syncthreads();                    // single barrier per step
        cur ^= 1;
    }
}

// ---------------------------------------------------------------------------
// K1: fused GEMM + sum-of-exp2, LDS-staged B (double-buffered).
// A = zsb [4096 x 128] bf16 (prescaled by log2e), register-resident per wave.
// B = Wvb [VPAD x 128] bf16 (zero-padded).  Block: 4 waves x 64 rows = 256
// rows x 12-13 groups of 64 N-cols.  Per group the block cooperatively DMAs
// the 16 KB B-tile into LDS via global_load_lds width=16 (contiguous 1 KB
// per wave-instr => coalesced), with an XOR-16 granule swizzle so the
// strided ds_read_b128 fragment reads are bank-conflict-free:
//   physical granule (r, q) holds logical granule (r, q ^ (r & 15)).
// Double-buffer: stage group g+1 while computing group g (one barrier/iter).
// Removes the round-1..3 bottleneck: 4x redundant per-wave B loads
// (787 MB of scattered L2 reads -> 197 MB coalesced + LDS broadcast).
// mfma_f32_16x16x32_bf16 layouts (HW-verified, guide §3):
//   A: lane holds A[m=lane&15][k=(lane>>4)*8 + j], j=0..7
//   B: lane holds B[n=lane&15][k=(lane>>4)*8 + j]
//   D: lane holds D[row=(lane>>4)*4 + r][col=lane&15], r=0..3
// ---------------------------------------------------------------------------
typedef __attribute__((ext_vector_type(8))) short bfrag;
typedef __attribute__((ext_vector_type(4))) float f32x4;

__global__ __launch_bounds__(256) void gemm_lse_kernel(const unsigned short* __restrict__ zsb,
                                                       const unsigned short* __restrict__ Wvb,
                                                       const float* __restrict__ bvs,
                                                       float* __restrict__ S) {
    __shared__ short ldsb[2][8192];          // 2 x 16 KB B tiles

    const int lane  = threadIdx.x & 63;
    const int wave  = threadIdx.x >> 6;
    const int col16 = lane & 15;
    const int quad  = lane >> 4;
    const int mbase = blockIdx.y * 256 + wave * 64;

    // A fragments: 4 M-subtiles x 4 K-chunks, register resident (64 VGPRs)
    bfrag a[4][4];
    const short* zss = reinterpret_cast<const short*>(zsb);
#pragma unroll
    for (int s = 0; s < 4; s++)
#pragma unroll
        for (int c = 0; c < 4; c++) {
            const short* p = zss + (long)(mbase + s * 16 + col16) * EMBED + c * 32 + quad * 8;
            a[s][c] = *reinterpret_cast<const bfrag*>(p);
        }

    float sums[16];
#pragma unroll
    for (int i = 0; i < 16; i++) sums[i] = 0.f;

    // group range for this x-block: 786 = 64*12 + 18
    const int x  = blockIdx.x;
    const int g0 = x * 12 + min(x, 18);
    const int g1 = g0 + 12 + (x < 18 ? 1 : 0);

    const short* wvs = reinterpret_cast<const short*>(Wvb);

    // stage group g's 16 KB B-tile into ldsb[buf] (swizzled, coalesced)
    auto stage = [&](int buf, int g) {
#pragma unroll
        for (int j = 0; j < 4; j++) {
            // this wave-instr covers physical granules s = (wave*4+j)*64 + lane
            // -> rows r = (wave*4+j)*4 + quad, phys col q = col16
            const int r   = (wave * 4 + j) * 4 + quad;
            const int swz = col16 ^ (r & 15);          // logical granule col
            const short* gp = wvs + (long)(g * 64 + r) * EMBED + swz * 8;
            __builtin_amdgcn_global_load_lds(
                (const __attribute__((address_space(1))) void*)gp,
                (__attribute__((address_space(3))) void*)&ldsb[buf][(wave * 4 + j) * 512],
                16, 0, 0);
        }
    };

    int cur = 0;
    stage(0, g0);

    for (int g = g0; g < g1; g++) {
        __syncthreads();                     // buf[cur] staged; prev reads done
        if (g + 1 < g1) stage(cur ^ 1, g + 1);

        const int colbase = g * 64;
        float bvl[4];
#pragma unroll
        for (int c = 0; c < 4; c++) bvl[c] = bvs[colbase + c * 16 + col16];

#pragma unroll
        for (int c = 0; c < 4; c++) {
            // fragment reads: logical (r = c*16+col16, kpart = kc*4+quad),
            // physical col = kpart ^ (r&15) = kpart ^ col16
            bfrag bf[4];
#pragma unroll
            for (int kc = 0; kc < 4; kc++)
                bf[kc] = *reinterpret_cast<const bfrag*>(
                    &ldsb[cur][(c * 16 + col16) * 128 + (((kc * 4 + quad) ^ col16) * 8)]);
#pragma unroll
            for (int s = 0; s < 4; s++) {
                f32x4 d = {bvl[c], bvl[c], bvl[c], bvl[c]};
#pragma unroll
                for (int kc = 0; kc < 4; kc++)
                    d = __builtin_amdgcn_mfma_f32_16x16x32_bf16(a[s][kc], bf[kc], d, 0, 0, 0);
#pragma unroll
                for (int r = 0; r < 4; r++)
                    sums[s * 4 + r] += fast_exp2(d[r]);
            }
        }
        cur ^= 1;
    }

    // reduce partial sums over the 16 columns, one atomic per row per block
#pragma unroll
    for (int s = 0; s < 4; s++) {
#pragma unroll
        for (int r = 0; r < 4; r++) {
            float v = sums[s * 4 + r];
            v += __shfl_xor(v, 1);
            v += __shfl_xor(v, 2);
            v += __shfl_xor(v, 4);
            v += __shfl_xor(v, 8);
            if (col16 == 0)
                atomicAdd(&S[mbase + s * 16 + quad * 4 + r], v);
        }
    }
}

// ---------------------------------------------------------------------------
// K2: yp[row] = ln2*(dot_scaled - log2(S[row])) + bv[y[row]], where
// dot_scaled = (bf16 zsb row) . (fp32 Wv[y] row)  -- zsb is z*log2e in bf16;
// the bf16 quantization adds only ~1e-3 to the target dot (budget 0.156).
// One wave per row; lane l handles elements {2l, 2l+1}.
// ---------------------------------------------------------------------------
__global__ __launch_bounds__(256) void tail_kernel(const unsigned short* __restrict__ zsb,
                                                   const float* __restrict__ Wv,
                                                   const float* __restrict__ bv,
                                                   const int* __restrict__ y,
                                                   const float* __restrict__ S,
                                                   float* __restrict__ out) {
    const int row  = blockIdx.x * 4 + (threadIdx.x >> 6);
    const int lane = threadIdx.x & 63;
    const int yv = y[row];
    const ushort2* zr = reinterpret_cast<const ushort2*>(zsb + (long)row * EMBED);
    const float2*  wr = reinterpret_cast<const float2*>(Wv + (long)yv * EMBED);
    ushort2 z2 = zr[lane];
    float2  w2 = wr[lane];
    float v = bf_raw2f(z2.x) * w2.x + bf_raw2f(z2.y) * w2.y;
    v += __shfl_xor(v, 32);
    v += __shfl_xor(v, 16);
    v += __shfl_xor(v, 8);
    v += __shfl_xor(v, 4);
    v += __shfl_xor(v, 2);
    v += __shfl_xor(v, 1);
    if (lane == 0)
        out[row] = LN2 * (v - fast_log2(S[row])) + bv[yv];
}

// ---------------------------------------------------------------------------
extern "C" void kernel_launch(void* const* d_in, const int* in_sizes, int n_in,
                              void* d_out, int out_size, void* d_ws, size_t ws_size,
                              hipStream_t stream) {
    const int*   zi     = (const int*)d_in[0];
    const int*   y      = (const int*)d_in[1];
    const float* latent = (const float*)d_in[2];
    const float* Wt     = (const float*)d_in[3];
    const float* bt     = (const float*)d_in[4];
    const float* Wv     = (const float*)d_in[5];
    const float* bv     = (const float*)d_in[6];
    float* out = (float*)d_out;

    char* ws = (char*)d_ws;
    // workspace layout (~14.3 MB total):
    unsigned short* zsb = (unsigned short*)ws;                         // 1 MB   @ 0
    float*          S   = (float*)(ws + (1u << 20));                   // 16 KB  @ 1M
    float*          bvs = (float*)(ws + (1u << 20) + (64u << 10));     // 197 KB @ 1M+64K
    unsigned short* wvb = (unsigned short*)(ws + (2u << 20));          // 12.28MB@ 2M

    setup_kernel<<<NBATCH + CONV_BLOCKS, 256, 0, stream>>>(zi, latent, Wt, bt, Wv, bv,
                                                           zsb, wvb, bvs, S);

    gemm_lse_kernel<<<dim3(GRIDX, GRIDY), 256, 0, stream>>>(zsb, wvb, bvs, S);

    tail_kernel<<<MROWS / 4, 256, 0, stream>>>(zsb, Wv, bv, y, S, out);
}

// Round 7
// 214.603 us; speedup vs baseline: 1.3472x; 1.0068x over previous
//
#include <hip/hip_runtime.h>
#include <hip/hip_bf16.h>
#include <hip/hip_fp16.h>

#define EMBED 128
#define TSTEPS 128
#define NBATCH 32
#define VDIM 50257
#define VPAD 50304            // 786 groups * 64 cols
#define MROWS 4096            // NBATCH * TSTEPS
#define NGROUPS 786           // VPAD / 64
#define GRIDX 64
#define GRIDY 16
#define MAXGRP 13             // max groups per x-block (786 = 64*12 + 18)
#define CONV_N4 ((VDIM * EMBED) / 4)          // 1608224 float4 elements
#define CONV_BLOCKS ((CONV_N4 + 255) / 256)   // 6283

static constexpr float LOG2E = 1.4426950408889634f;
static constexpr float LN2   = 0.6931471805599453f;

__device__ __forceinline__ float fast_exp2(float x) {
#if __has_builtin(__builtin_amdgcn_exp2f)
    return __builtin_amdgcn_exp2f(x);
#else
    return exp2f(x);
#endif
}
__device__ __forceinline__ float fast_log2(float x) {
#if __has_builtin(__builtin_amdgcn_logf)
    return __builtin_amdgcn_logf(x);
#else
    return log2f(x);
#endif
}
__device__ __forceinline__ unsigned short f2bf_raw(float f) {
    __hip_bfloat16 h = __float2bfloat16(f);
    union { __hip_bfloat16 b; unsigned short u; } cvt;
    cvt.b = h;
    return cvt.u;
}
__device__ __forceinline__ float bf_raw2f(unsigned short u) {
    union { unsigned int u; float f; } cvt;
    cvt.u = ((unsigned int)u) << 16;
    return cvt.f;
}

// ---------------------------------------------------------------------------
// K0 (fused setup): blocks [0,32) = sequential scan (one batch chain each);
// blocks [32, 32+CONV_BLOCKS) convert Wv fp32->bf16, write the bf16 zero pad
// rows [VDIM,VPAD), build the prescaled/padded bias array, and zero S.
//
// Scan: e = tid>>1, h = tid&1 -> the two k-halves of an output element sit
// in ADJACENT lanes (half-dots combine with one shfl_xor); z is ping-pong
// buffered so each step needs exactly ONE __syncthreads.  The fp32 summation
// order ((zc + s_h0) + s_h1) + bt and libm tanhf are bit-exact vs rounds
// 1/3/5: the recurrence is a ~1e6x error amplifier (round-4 fast_tanh
// failure) — do not perturb the trajectory.
// ---------------------------------------------------------------------------
__global__ __launch_bounds__(256) void setup_kernel(const int* __restrict__ zi,
                                                    const float* __restrict__ latent,
                                                    const float* __restrict__ Wt,
                                                    const float* __restrict__ bt,
                                                    const float* __restrict__ Wv,
                                                    const float* __restrict__ bv,
                                                    unsigned short* __restrict__ zsb,
                                                    unsigned short* __restrict__ Wvb,
                                                    float* __restrict__ bvs,
                                                    float* __restrict__ S) {
    if (blockIdx.x >= NBATCH) {
        const int cb = blockIdx.x - NBATCH;
        if (cb == 0) {                      // zero the S accumulator
#pragma unroll
            for (int i = 0; i < MROWS / 256; i++)
                S[i * 256 + threadIdx.x] = 0.f;
        }
        if (cb == 1) {                      // zero pad rows of Wvb
            const int base4 = (VDIM * EMBED) / 4;     // first pad ushort4
            const int npad4 = ((VPAD - VDIM) * EMBED) / 4;
            for (int i = threadIdx.x; i < npad4; i += 256)
                reinterpret_cast<ushort4*>(Wvb)[base4 + i] = make_ushort4(0, 0, 0, 0);
        }
        const int idx = cb * 256 + threadIdx.x;
        if (idx < VPAD)                     // prescaled, padded bias
            bvs[idx] = (idx < VDIM) ? bv[idx] * LOG2E : -1e30f;
        if (idx < CONV_N4) {
            float4 v = reinterpret_cast<const float4*>(Wv)[idx];
            ushort4 o;
            o.x = f2bf_raw(v.x); o.y = f2bf_raw(v.y);
            o.z = f2bf_raw(v.z); o.w = f2bf_raw(v.w);
            reinterpret_cast<ushort4*>(Wvb)[idx] = o;
        }
        return;
    }

    // ---- scan path: one block per batch element ----
    __shared__ float zbuf[2][EMBED];
    const int b = blockIdx.x;
    const int e = threadIdx.x >> 1;     // output element 0..127
    const int h = threadIdx.x & 1;      // k-half

    // cache Wt[e][h*64 .. h*64+63] in registers (64 VGPRs)
    float4 wrow[16];
    const float4* wt4 = reinterpret_cast<const float4*>(Wt + e * EMBED + h * 64);
#pragma unroll
    for (int i = 0; i < 16; i++) wrow[i] = wt4[i];
    const float bte = bt[e];

    if (h == 0) zbuf[0][e] = latent[zi[b] * EMBED + e];
    __syncthreads();

    int cur = 0;
    for (int t = 0; t < TSTEPS; t++) {
        const float zc = zbuf[cur][e];      // lane pairs broadcast
        const long row = (long)b * TSTEPS + t;
        if (h == 0)                         // emit pre-update z (bf16 * log2e)
            zsb[row * EMBED + e] = f2bf_raw(zc * LOG2E);

        // half-dot over k in [h*64, h*64+64)
        const float4* z4 = reinterpret_cast<const float4*>(&zbuf[cur][h * 64]);
        float4 acc = {0.f, 0.f, 0.f, 0.f};
#pragma unroll
        for (int i = 0; i < 16; i++) {
            float4 zv = z4[i];
            acc.x += zv.x * wrow[i].x;
            acc.y += zv.y * wrow[i].y;
            acc.z += zv.z * wrow[i].z;
            acc.w += zv.w * wrow[i].w;
        }
        float v = acc.x + acc.y + acc.z + acc.w;
        float p = __shfl_xor(v, 1);         // partner half (same e, other h)
        float sA = h ? p : v;               // first-half dot
        float sB = h ? v : p;               // second-half dot
        // summation order identical to rounds 1/3/5 (bit-exact trajectory)
        float znew = tanhf(((zc + sA) + sB) + bte);   // exact libm tanh
        if (h == 0) zbuf[cur ^ 1][e] = znew;
        __syncthreads();                    // single barrier per step
        cur ^= 1;
    }
}

// ---------------------------------------------------------------------------
// K1: fused GEMM + sum-of-exp2, LDS-staged B (double-buffered).
// A = zsb [4096 x 128] bf16 (prescaled by log2e), register-resident per wave.
// B = Wvb [VPAD x 128] bf16 (zero-padded).  Block: 4 waves x 64 rows = 256
// rows x 12-13 groups of 64 N-cols; 16 KB B-tiles DMAd to LDS via
// global_load_lds width=16 with an XOR-16 granule swizzle (conflict-free
// ds_read_b128), double-buffered, one barrier per group.
// Round-7 changes (VALU/stall trim; S numerics unchanged at fp32 rounding):
//  * bias slice staged to LDS in the prologue -> no global loads (and no
//    vmcnt stalls) inside the group loop.
//  * zero-C init: all 16 MFMA chains start from ONE shared zero quad
//    (kills 64 per-group v_mov accumulator splats); bias applied after as
//    sums = fma(exp2(d), exp2(bias*log2e), sums)  [exp2(d)*exp2(b)=exp2(d+b);
//    pad bias -1e30 -> factor 0].
//  * kc-outer / s-inner MFMA order with d[4] live: consecutive MFMAs are
//    4-independent (dep distance 4) instead of 4-deep dependent chains.
// mfma_f32_16x16x32_bf16 layouts (HW-verified, guide §3):
//   A: lane holds A[m=lane&15][k=(lane>>4)*8 + j], j=0..7
//   B: lane holds B[n=lane&15][k=(lane>>4)*8 + j]
//   D: lane holds D[row=(lane>>4)*4 + r][col=lane&15], r=0..3
// ---------------------------------------------------------------------------
typedef __attribute__((ext_vector_type(8))) short bfrag;
typedef __attribute__((ext_vector_type(4))) float f32x4;

__global__ __launch_bounds__(256) void gemm_lse_kernel(const unsigned short* __restrict__ zsb,
                                                       const unsigned short* __restrict__ Wvb,
                                                       const float* __restrict__ bvs,
                                                       float* __restrict__ S) {
    __shared__ short ldsb[2][8192];          // 2 x 16 KB B tiles
    __shared__ float ldsbias[MAXGRP * 64];   // this block's bias slice (3.3 KB)

    const int lane  = threadIdx.x & 63;
    const int wave  = threadIdx.x >> 6;
    const int col16 = lane & 15;
    const int quad  = lane >> 4;
    const int mbase = blockIdx.y * 256 + wave * 64;

    // group range for this x-block: 786 = 64*12 + 18
    const int x  = blockIdx.x;
    const int g0 = x * 12 + min(x, 18);
    const int g1 = g0 + 12 + (x < 18 ? 1 : 0);
    const int nbias = (g1 - g0) * 64;

    // prologue: stage this block's bias slice into LDS (visible after the
    // loop's first __syncthreads)
    for (int i = threadIdx.x; i < nbias; i += 256)
        ldsbias[i] = bvs[g0 * 64 + i];

    // A fragments: 4 M-subtiles x 4 K-chunks, register resident (64 VGPRs)
    bfrag a[4][4];
    const short* zss = reinterpret_cast<const short*>(zsb);
#pragma unroll
    for (int s = 0; s < 4; s++)
#pragma unroll
        for (int c = 0; c < 4; c++) {
            const short* p = zss + (long)(mbase + s * 16 + col16) * EMBED + c * 32 + quad * 8;
            a[s][c] = *reinterpret_cast<const bfrag*>(p);
        }

    float sums[16];
#pragma unroll
    for (int i = 0; i < 16; i++) sums[i] = 0.f;

    const short* wvs = reinterpret_cast<const short*>(Wvb);

    // stage group g's 16 KB B-tile into ldsb[buf] (swizzled, coalesced)
    auto stage = [&](int buf, int g) {
#pragma unroll
        for (int j = 0; j < 4; j++) {
            // this wave-instr covers physical granules s = (wave*4+j)*64 + lane
            // -> rows r = (wave*4+j)*4 + quad, phys col q = col16
            const int r   = (wave * 4 + j) * 4 + quad;
            const int swz = col16 ^ (r & 15);          // logical granule col
            const short* gp = wvs + (long)(g * 64 + r) * EMBED + swz * 8;
            __builtin_amdgcn_global_load_lds(
                (const __attribute__((address_space(1))) void*)gp,
                (__attribute__((address_space(3))) void*)&ldsb[buf][(wave * 4 + j) * 512],
                16, 0, 0);
        }
    };

    int cur = 0;
    stage(0, g0);

    const f32x4 dzero = {0.f, 0.f, 0.f, 0.f};

    for (int g = g0; g < g1; g++) {
        __syncthreads();                     // buf[cur] + bias staged; prev reads done
        if (g + 1 < g1) stage(cur ^ 1, g + 1);

        const float* biasg = &ldsbias[(g - g0) * 64];

#pragma unroll
        for (int c = 0; c < 4; c++) {
            // fragment reads: logical (r = c*16+col16, kpart = kc*4+quad),
            // physical col = kpart ^ (r&15) = kpart ^ col16
            bfrag bf[4];
#pragma unroll
            for (int kc = 0; kc < 4; kc++)
                bf[kc] = *reinterpret_cast<const bfrag*>(
                    &ldsb[cur][(c * 16 + col16) * 128 + (((kc * 4 + quad) ^ col16) * 8)]);

            const float eb = fast_exp2(biasg[c * 16 + col16]);  // exp2(bias*log2e); 0 for pad

            // kc-outer, s-inner: consecutive MFMAs are independent (4 chains)
            f32x4 d[4];
#pragma unroll
            for (int s = 0; s < 4; s++)
                d[s] = __builtin_amdgcn_mfma_f32_16x16x32_bf16(a[s][0], bf[0], dzero, 0, 0, 0);
#pragma unroll
            for (int kc = 1; kc < 4; kc++)
#pragma unroll
                for (int s = 0; s < 4; s++)
                    d[s] = __builtin_amdgcn_mfma_f32_16x16x32_bf16(a[s][kc], bf[kc], d[s], 0, 0, 0);

#pragma unroll
            for (int s = 0; s < 4; s++)
#pragma unroll
                for (int r = 0; r < 4; r++)
                    sums[s * 4 + r] = fmaf(fast_exp2(d[s][r]), eb, sums[s * 4 + r]);
        }
        cur ^= 1;
    }

    // reduce partial sums over the 16 columns, one atomic per row per block
#pragma unroll
    for (int s = 0; s < 4; s++) {
#pragma unroll
        for (int r = 0; r < 4; r++) {
            float v = sums[s * 4 + r];
            v += __shfl_xor(v, 1);
            v += __shfl_xor(v, 2);
            v += __shfl_xor(v, 4);
            v += __shfl_xor(v, 8);
            if (col16 == 0)
                atomicAdd(&S[mbase + s * 16 + quad * 4 + r], v);
        }
    }
}

// ---------------------------------------------------------------------------
// K2: yp[row] = ln2*(dot_scaled - log2(S[row])) + bv[y[row]], where
// dot_scaled = (bf16 zsb row) . (fp32 Wv[y] row)  -- zsb is z*log2e in bf16;
// the bf16 quantization adds only ~1e-3 to the target dot (budget 0.156).
// One wave per row; lane l handles elements {2l, 2l+1}.
// ---------------------------------------------------------------------------
__global__ __launch_bounds__(256) void tail_kernel(const unsigned short* __restrict__ zsb,
                                                   const float* __restrict__ Wv,
                                                   const float* __restrict__ bv,
                                                   const int* __restrict__ y,
                                                   const float* __restrict__ S,
                                                   float* __restrict__ out) {
    const int row  = blockIdx.x * 4 + (threadIdx.x >> 6);
    const int lane = threadIdx.x & 63;
    const int yv = y[row];
    const ushort2* zr = reinterpret_cast<const ushort2*>(zsb + (long)row * EMBED);
    const float2*  wr = reinterpret_cast<const float2*>(Wv + (long)yv * EMBED);
    ushort2 z2 = zr[lane];
    float2  w2 = wr[lane];
    float v = bf_raw2f(z2.x) * w2.x + bf_raw2f(z2.y) * w2.y;
    v += __shfl_xor(v, 32);
    v += __shfl_xor(v, 16);
    v += __shfl_xor(v, 8);
    v += __shfl_xor(v, 4);
    v += __shfl_xor(v, 2);
    v += __shfl_xor(v, 1);
    if (lane == 0)
        out[row] = LN2 * (v - fast_log2(S[row])) + bv[yv];
}

// ---------------------------------------------------------------------------
extern "C" void kernel_launch(void* const* d_in, const int* in_sizes, int n_in,
                              void* d_out, int out_size, void* d_ws, size_t ws_size,
                              hipStream_t stream) {
    const int*   zi     = (const int*)d_in[0];
    const int*   y      = (const int*)d_in[1];
    const float* latent = (const float*)d_in[2];
    const float* Wt     = (const float*)d_in[3];
    const float* bt     = (const float*)d_in[4];
    const float* Wv     = (const float*)d_in[5];
    const float* bv     = (const float*)d_in[6];
    float* out = (float*)d_out;

    char* ws = (char*)d_ws;
    // workspace layout (~14.3 MB total):
    unsigned short* zsb = (unsigned short*)ws;                         // 1 MB   @ 0
    float*          S   = (float*)(ws + (1u << 20));                   // 16 KB  @ 1M
    float*          bvs = (float*)(ws + (1u << 20) + (64u << 10));     // 197 KB @ 1M+64K
    unsigned short* wvb = (unsigned short*)(ws + (2u << 20));          // 12.28MB@ 2M

    setup_kernel<<<NBATCH + CONV_BLOCKS, 256, 0, stream>>>(zi, latent, Wt, bt, Wv, bv,
                                                           zsb, wvb, bvs, S);

    gemm_lse_kernel<<<dim3(GRIDX, GRIDY), 256, 0, stream>>>(zsb, wvb, bvs, S);

    tail_kernel<<<MROWS / 4, 256, 0, stream>>>(zsb, Wv, bv, y, S, out);
}